// Round 4
// baseline (49.999 us; speedup 1.0000x reference)
//
#include <hip/hip_runtime.h>

// IFNode multi-step forward, hard reset.
// x: (T=16, N=32, F=65536) f32. out: spikes, same shape/dtype.
// Per (n,f): v=0; for t: h=v+x[t]; spike=(h>=1); v = spike?0:h; out[t]=spike.
//
// R2/R3 findings: MALL ignores NT hints on loads (FETCH pinned at 65.5MB =
// half the 128MiB input; in+out = 268MB ~= L3 size, replacement keeps half).
// Traffic floor ~196MB/replay. This round: issue-side — 2 independent
// v-chains per thread (columns idx and idx+nf4/2) to double outstanding
// loads; nt stores kept (R1->R2 win). Both streams stride-16B coalesced.

#define T_STEPS 16

typedef float v4f __attribute__((ext_vector_type(4)));

__device__ __forceinline__ void step4(v4f xv, v4f& v, v4f& s) {
    float h;
    h = v.x + xv.x; s.x = (h >= 1.0f) ? 1.0f : 0.0f; v.x = (h >= 1.0f) ? 0.0f : h;
    h = v.y + xv.y; s.y = (h >= 1.0f) ? 1.0f : 0.0f; v.y = (h >= 1.0f) ? 0.0f : h;
    h = v.z + xv.z; s.z = (h >= 1.0f) ? 1.0f : 0.0f; v.z = (h >= 1.0f) ? 0.0f : h;
    h = v.w + xv.w; s.w = (h >= 1.0f) ? 1.0f : 0.0f; v.w = (h >= 1.0f) ? 0.0f : h;
}

__global__ __launch_bounds__(256) void ifnode_kernel(
    const v4f* __restrict__ x4, v4f* __restrict__ o4, int nf4) {
    int idx = blockIdx.x * blockDim.x + threadIdx.x;
    int half = nf4 >> 1;
    if (idx >= half) return;

    int ia = idx;          // chain A: first half of the feature axis
    int ib = idx + half;   // chain B: second half

    v4f va = {0.f, 0.f, 0.f, 0.f};
    v4f vb = {0.f, 0.f, 0.f, 0.f};

#pragma unroll
    for (int t = 0; t < T_STEPS; ++t) {
        size_t base = (size_t)t * nf4;
        v4f xa = x4[base + ia];
        v4f xb = x4[base + ib];
        v4f sa, sb;
        step4(xa, va, sa);
        step4(xb, vb, sb);
        __builtin_nontemporal_store(sa, &o4[base + ia]);
        __builtin_nontemporal_store(sb, &o4[base + ib]);
    }
}

extern "C" void kernel_launch(void* const* d_in, const int* in_sizes, int n_in,
                              void* d_out, int out_size, void* d_ws, size_t ws_size,
                              hipStream_t stream) {
    const float* x = (const float*)d_in[0];
    float* out = (float*)d_out;

    int nf = in_sizes[0] / T_STEPS;   // 32*65536 = 2097152
    int nf4 = nf / 4;                 // 524288 v4f per step
    int half = nf4 / 2;               // 262144 threads, 2 chains each

    int block = 256;
    int grid = (half + block - 1) / block;  // 1024

    ifnode_kernel<<<grid, block, 0, stream>>>(
        (const v4f*)x, (v4f*)out, nf4);
}

// Round 5
// 45.141 us; speedup vs baseline: 1.1076x; 1.1076x over previous
//
#include <hip/hip_runtime.h>

// IFNode multi-step forward, hard reset.
// x: (T=16, N=32, F=65536) f32. out: spikes, same shape/dtype.
// Per (n,f): v=0; for t: h=v+x[t]; spike=(h>=1); v = spike?0:h; out[t]=spike.
//
// Findings so far:
//  R1->R2: nt stores cut WRITE 150->131MB (no RFO/write-amp), dur 50.6->45.6.
//  R3: nt LOADS don't steer the MALL (FETCH pinned 65.5MB = half the input;
//      in+out = 262MiB ~ L3 size -> output allocation evicts half the input).
//  R4: 2-way per-thread ILP regressed (two streams 32MiB apart, half waves).
// This round: single-chain R2 structure, but stores via inline asm with the
// full cache-bypass policy "sc0 sc1 nt" (system scope + non-temporal) to try
// to suppress MALL allocation of the output stream. If FETCH->0, HBM traffic
// becomes write-only (~131MB).

#define T_STEPS 16

typedef float v4f __attribute__((ext_vector_type(4)));

__global__ __launch_bounds__(256) void ifnode_kernel(
    const v4f* __restrict__ x4, v4f* __restrict__ o4, int nf4) {
    int idx = blockIdx.x * blockDim.x + threadIdx.x;
    if (idx >= nf4) return;

    v4f v = {0.f, 0.f, 0.f, 0.f};

#pragma unroll
    for (int t = 0; t < T_STEPS; ++t) {
        size_t base = (size_t)t * nf4;
        v4f xv = x4[base + idx];
        v4f s;

        float h;
        h = v.x + xv.x; s.x = (h >= 1.0f) ? 1.0f : 0.0f; v.x = (h >= 1.0f) ? 0.0f : h;
        h = v.y + xv.y; s.y = (h >= 1.0f) ? 1.0f : 0.0f; v.y = (h >= 1.0f) ? 0.0f : h;
        h = v.z + xv.z; s.z = (h >= 1.0f) ? 1.0f : 0.0f; v.z = (h >= 1.0f) ? 0.0f : h;
        h = v.w + xv.w; s.w = (h >= 1.0f) ? 1.0f : 0.0f; v.w = (h >= 1.0f) ? 0.0f : h;

        // Store with system-scope + non-temporal policy: try to keep the
        // output stream from allocating in L2/MALL so the input stays
        // cache-resident across graph replays.
        v4f* p = &o4[base + idx];
        asm volatile("global_store_dwordx4 %0, %1, off sc0 sc1 nt"
                     :
                     : "v"(p), "v"(s)
                     : "memory");
    }
}

extern "C" void kernel_launch(void* const* d_in, const int* in_sizes, int n_in,
                              void* d_out, int out_size, void* d_ws, size_t ws_size,
                              hipStream_t stream) {
    const float* x = (const float*)d_in[0];
    float* out = (float*)d_out;

    int nf = in_sizes[0] / T_STEPS;   // 32*65536 = 2097152
    int nf4 = nf / 4;                 // 524288 v4f per step

    int block = 256;
    int grid = (nf4 + block - 1) / block;  // 2048

    ifnode_kernel<<<grid, block, 0, stream>>>(
        (const v4f*)x, (v4f*)out, nf4);
}